// Round 1
// 62.638 us; speedup vs baseline: 1.0108x; 1.0108x over previous
//
#include <hip/hip_runtime.h>
#include <math.h>

#define NN 256
#define NF 24
#define RCUT 6.0f
#define PI_F 3.14159265358979323846f
#define CS 0.27415568f   // (pi/6)^2 : u = CS * sq_jk

// fc(sq) = 0.5*(1+cos(pi*sqrt(sq)/6)) as even Taylor in u = CS*sq; |err|<=5.2e-5
__device__ __forceinline__ float fc_poly(float u) {
    float p = 1.0438378e-9f;
    p = fmaf(p, u, -1.3778659e-7f);
    p = fmaf(p, u,  1.2400794e-5f);
    p = fmaf(p, u, -6.9444444e-4f);
    p = fmaf(p, u,  2.0833333e-2f);
    p = fmaf(p, u, -0.25f);
    p = fmaf(p, u,  1.0f);
    return p;
}

// grid (NN, B): BOTH eta halves merged into one block. All 8 waves split the
// triple t-range; each pair iteration shares cost/s/fc_poly between etas and
// forks only at the exponentials. Waves 0 and 1 do the O(m) moment pass for
// eta0 / eta1 respectively, after their triple share.
__global__ __launch_bounds__(512, 4) void feat_kernel(
    const float* __restrict__ Z,       // [N]
    const float* __restrict__ coords,  // [B,N,3]
    float* __restrict__ out)           // [B,N,24]
{
    const int i = blockIdx.x, b = blockIdx.y;
    const int tid = threadIdx.x, lane = tid & 63, wave = tid >> 6;

    __shared__ float4 geo[NN + 128];   // compacted: ux,uy,uz,r
    __shared__ float4 ab2[NN + 128];   // compacted: W0=fc*exp(-.01*r2), W1=fc*exp(-.1*r2), r2, pad
    __shared__ int   wave_cnt[4];
    __shared__ float rad[4][7];
    __shared__ float red[8][8][8];     // triple partials [wave][octet][feat 0..7]
    __shared__ float mom[2][64][36];   // moment partials per eta (waves 0/1)
    __shared__ float momsum[2][36];

    const float* cb = coords + (size_t)b * NN * 3;
    const float xi = cb[i * 3 + 0], yi = cb[i * 3 + 1], zi = cb[i * 3 + 2];

    // ---- setup: waves 0..3, j = tid ----
    float dx = 0, dy = 0, dz = 0, r2 = 0, r = 0, fc = 0;
    bool incut = false;
    if (tid < NN) {
        const float xj = cb[tid * 3 + 0], yj = cb[tid * 3 + 1], zj = cb[tid * 3 + 2];
        dx = xi - xj; dy = yi - yj; dz = zi - zj;
        r2 = dx * dx + dy * dy + dz * dz;
        r  = sqrtf(r2);
        incut = (tid != i) && (r < RCUT);
        fc = incut ? 0.5f * (__cosf((PI_F / RCUT) * r) + 1.0f) : 0.0f;
        {   // radial features (once per (b,i) now)
            float racc[7];
            racc[0] = fc;
            racc[1] = __expf(-0.1f * r2) * fc;
            racc[2] = __expf(-1.0f * r2) * fc;
            const float d = r - 2.0f;
            racc[3] = __expf(-0.1f * d * d) * fc;
            racc[4] = __expf(-1.0f * d * d) * fc;
            racc[5] = __cosf(r) * fc;
            racc[6] = __cosf(2.0f * r) * fc;
#pragma unroll
            for (int t = 0; t < 7; t++) {
                float v = racc[t];
                for (int off = 32; off > 0; off >>= 1) v += __shfl_down(v, off, 64);
                if (lane == 0) rad[wave][t] = v;
            }
        }
        const unsigned long long bal = __ballot(incut);
        if (lane == 0) wave_cnt[wave] = __popcll(bal);
    }
    __syncthreads();

    const int m = wave_cnt[0] + wave_cnt[1] + wave_cnt[2] + wave_cnt[3];
    if (tid < NN && incut) {
        const unsigned long long bal = __ballot(incut);
        int base = 0;
#pragma unroll
        for (int w = 0; w < 4; w++) if (w < wave) base += wave_cnt[w];
        const int p = base + __popcll(bal & ((1ULL << lane) - 1ULL));
        const float rinv = 1.0f / r;
        geo[p] = make_float4(dx * rinv, dy * rinv, dz * rinv, r);
        ab2[p] = make_float4(fc * __expf(-0.01f * r2), fc * __expf(-0.1f * r2), r2, 0.0f);
    }
    __syncthreads();
    const int Rext = (m >= 2) ? ((m - 1) >> 1) : 0;   // unwrap extension
    for (int sx = tid; sx < Rext; sx += 512) { geo[m + sx] = geo[sx]; ab2[m + sx] = ab2[sx]; }
    __syncthreads();

    // ---- triple features (BOTH etas): round-robin pairs, t-split 8 ways ----
    float acc[8] = {0, 0, 0, 0, 0, 0, 0, 0};
    if (m >= 2) {
        const int Rfull = (m - 1) >> 1;
        const int tlo = 1 + ((Rfull * wave) >> 3);
        const int thi = (Rfull * (wave + 1)) >> 3;
        const int mh = m >> 1;
        const bool doHalf = (wave == 7) && ((m & 1) == 0);
        for (int rnd = 0; rnd < 4; ++rnd) {
            const int jj = lane + (rnd << 6);
            if (jj >= m) break;
            const float4 gj = geo[jj];
            const float4 aj = ab2[jj];
            const float r2j = aj.z;
            const float W0j = aj.x, W1j = aj.y;
            const float gw2 = -2.0f * gj.w;
            const int tend = thi + ((doHalf && jj < mh) ? 1 : 0);
            for (int t = tlo; t <= tend; ++t) {
                const int kk = jj + ((t > thi) ? mh : t);
                const float4 g = geo[kk];
                const float4 a = ab2[kk];
                const float cost = fmaf(gj.x, g.x, fmaf(gj.y, g.y, gj.z * g.z));
                const float s = fmaf(gw2 * g.w, cost, r2j + a.z);   // sq_jk
                const float pfc = fc_poly(CS * s);
                const float fcjk = (s < 36.0f) ? pfc : 0.0f;
                const float t0 = fcjk * __expf(-0.01f * s);
                const float t1 = fcjk * __expf(-0.1f * s);
                const float w30 = (W0j * a.x) * t0;
                const float w31 = (W1j * a.y) * t1;
                const float c1m = 1.0f - cost, c1p = 1.0f + cost;
                const float c2m = c1m * c1m, c2p = c1p * c1p;
                const float c4m = c2m * c2m, c4p = c2p * c2p;
                acc[0] += c1m * w30;  acc[1] += c1p * w30;
                acc[2] += c4m * w30;  acc[3] += c4p * w30;
                acc[4] += c1m * w31;  acc[5] += c1p * w31;
                acc[6] += c4m * w31;  acc[7] += c4p * w31;
            }
        }
    }
#pragma unroll
    for (int t = 0; t < 8; t++) {
        float v = acc[t];
        v += __shfl_down(v, 32, 64);
        v += __shfl_down(v, 16, 64);
        v += __shfl_down(v, 8, 64);
        acc[t] = v;
    }
    if (lane < 8) {
#pragma unroll
        for (int t = 0; t < 8; t++) red[wave][lane][t] = acc[t];
    }

    // ---- O(m) moment pass: wave 0 -> eta .01, wave 1 -> eta .1 ----
    if (wave < 2) {
        float mm[36];
#pragma unroll
        for (int q = 0; q < 36; q++) mm[q] = 0.0f;
        for (int rnd = 0; rnd < 4; ++rnd) {
            const int jj = lane + (rnd << 6);
            if (jj >= m) break;
            const float4 g = geo[jj];
            const float4 a = ab2[jj];
            const float w = wave ? a.y : a.x;
            const float x = g.x, y = g.y, z = g.z;
            mm[0] += w;
            const float wx = w * x, wy = w * y, wz = w * z;
            mm[1] += wx; mm[2] += wy; mm[3] += wz;
            const float wxx = wx * x, wxy = wx * y, wxz = wx * z;
            const float wyy = wy * y, wyz = wy * z, wzz = wz * z;
            mm[4] += wxx; mm[5] += wxy; mm[6] += wxz;
            mm[7] += wyy; mm[8] += wyz; mm[9] += wzz;
            const float wxxx = wxx * x, wxxy = wxx * y, wxxz = wxx * z;
            const float wxyy = wxy * y, wxyz = wxy * z, wxzz = wxz * z;
            const float wyyy = wyy * y, wyyz = wyy * z, wyzz = wyz * z, wzzz = wzz * z;
            mm[10] += wxxx; mm[11] += wxxy; mm[12] += wxxz; mm[13] += wxyy;
            mm[14] += wxyz; mm[15] += wxzz; mm[16] += wyyy; mm[17] += wyyz;
            mm[18] += wyzz; mm[19] += wzzz;
            mm[20] += wxxx * x; mm[21] += wxxx * y; mm[22] += wxxx * z;
            mm[23] += wxxy * y; mm[24] += wxxy * z; mm[25] += wxxz * z;
            mm[26] += wxyy * y; mm[27] += wxyy * z; mm[28] += wxyz * z;
            mm[29] += wxzz * z; mm[30] += wyyy * y; mm[31] += wyyy * z;
            mm[32] += wyyz * z; mm[33] += wyzz * z; mm[34] += wzzz * z;
            mm[35] = fmaf(w, w, mm[35]);              // diagonal D
        }
#pragma unroll
        for (int q = 0; q < 36; q++) mom[wave][lane][q] = mm[q];
        if (lane < 36) {                               // lockstep intra-wave reduce
            float v0 = 0, v1 = 0, v2 = 0, v3 = 0;
#pragma unroll
            for (int j = 0; j < 64; j += 4) {
                v0 += mom[wave][j + 0][lane]; v1 += mom[wave][j + 1][lane];
                v2 += mom[wave][j + 2][lane]; v3 += mom[wave][j + 3][lane];
            }
            momsum[wave][lane] = (v0 + v1) + (v2 + v3);
        }
    }
    __syncthreads();

    // ---- epilogue ----
    float* ob = out + ((size_t)b * NN + i) * NF;
    if (tid < 64) {
        const int f = tid >> 3, s = tid & 7;   // f: 0..7 = [e][zeta/lam]
        float v = 0.0f;
#pragma unroll
        for (int w = 0; w < 8; w++) v += red[w][s][f];
        v += __shfl_down(v, 4, 8);
        v += __shfl_down(v, 2, 8);
        v += __shfl_down(v, 1, 8);
        if (s == 0) {
            const int e = f >> 2, ff = f & 3;
            v *= (ff >= 2) ? 0.25f : 2.0f;   // x2 unordered; 2^(1-4)=0.125 for z4
            ob[8 + 4 * e + ff] = v;
        }
    } else if (tid < 72) {
        const int sub = tid - 64;          // 0..7
        const int e = sub >> 2, ss = sub & 3;
        const float* M = momsum[e];
        const float S0 = M[0] * M[0];
        const float S1 = M[1] * M[1] + M[2] * M[2] + M[3] * M[3];
        const float S2 = M[4] * M[4] + M[7] * M[7] + M[9] * M[9]
                       + 2.f * (M[5] * M[5] + M[6] * M[6] + M[8] * M[8]);
        const float S3 = M[10] * M[10] + M[16] * M[16] + M[19] * M[19]
                       + 3.f * (M[11] * M[11] + M[12] * M[12] + M[13] * M[13]
                              + M[15] * M[15] + M[17] * M[17] + M[18] * M[18])
                       + 6.f * M[14] * M[14];
        const float S4 = M[20] * M[20] + M[30] * M[30] + M[34] * M[34]
                       + 4.f * (M[21] * M[21] + M[22] * M[22] + M[26] * M[26]
                              + M[29] * M[29] + M[31] * M[31] + M[33] * M[33])
                       + 6.f * (M[23] * M[23] + M[25] * M[25] + M[32] * M[32])
                       + 12.f * (M[24] * M[24] + M[27] * M[27] + M[28] * M[28]);
        const float D = M[35];
        const float lam = (ss & 1) ? 1.0f : -1.0f;
        float v;
        if (ss < 2) v = S0 + lam * S1 - (1.0f + lam) * D;
        else        v = 0.125f * (S0 + 6.f * S2 + S4 + lam * 4.f * (S1 + S3)
                                  - ((ss == 3) ? 16.f * D : 0.0f));
        ob[16 + 4 * e + ss] = v;
    } else if (tid < 79) {
        const int t = tid - 72;
        ob[1 + t] = rad[0][t] + rad[1][t] + rad[2][t] + rad[3][t];
    } else if (tid == 79) {
        ob[0] = Z[i];
    }
}

extern "C" void kernel_launch(void* const* d_in, const int* in_sizes, int n_in,
                              void* d_out, int out_size, void* d_ws, size_t ws_size,
                              hipStream_t stream) {
    const float* Z = (const float*)d_in[0];       // [256]
    const float* coords = (const float*)d_in[1];  // [2,256,3]
    float* out = (float*)d_out;                   // [2,256,24]
    feat_kernel<<<dim3(NN, 2), dim3(512), 0, stream>>>(Z, coords, out);
}